// Round 8
// baseline (392.924 us; speedup 1.0000x reference)
//
#include <hip/hip_runtime.h>
#include <stdint.h>

#define S_DIM 8192
#define K_DIM 4096
#define N_DIM 4096

#define BM 128
#define BN 256
#define BKB 64               // bytes of K per ring tile = ONE 16x16x64 k-step
#define NT (K_DIM / BKB)     // 64 tiles
#define RD 3                 // ring depth (stage t+1 while computing t)

typedef int v4i __attribute__((ext_vector_type(4)));

// ---------------------------------------------------------------------------
// One launch: pack x (int32->int8), pack w, and copy scale_y to the output
// tail. Pack destination is contiguous in ws: [x packed | w packed].
__global__ void prep(const int* __restrict__ x, const int* __restrict__ w,
                     const float* __restrict__ sy,
                     int* __restrict__ dst, float* __restrict__ out) {
    const int nx = S_DIM * K_DIM / 4;
    const int nw = N_DIM * K_DIM / 4;
    int i = blockIdx.x * 256 + threadIdx.x;
    if (i < nx) {
        int4 a = ((const int4*)x)[i];
        dst[i] = (a.x & 0xFF) | ((a.y & 0xFF) << 8) | ((a.z & 0xFF) << 16)
               | ((a.w & 0xFF) << 24);
    } else if (i < nx + nw) {
        int4 a = ((const int4*)w)[i - nx];
        dst[i] = (a.x & 0xFF) | ((a.y & 0xFF) << 8) | ((a.z & 0xFF) << 16)
               | ((a.w & 0xFF) << 24);
    } else {
        int j = i - nx - nw;
        if (j < S_DIM) out[(size_t)S_DIM * N_DIM + j] = sy[j];
    }
}

// scale_y tail only (used by the no-workspace fallback path)
__global__ void copy_sy(const float* __restrict__ sy, float* __restrict__ out) {
    int i = blockIdx.x * blockDim.x + threadIdx.x;
    if (i < S_DIM) out[(size_t)S_DIM * N_DIM + i] = sy[i];
}

// ---------------------------------------------------------------------------
__device__ __forceinline__ void g2lds16(const void* g, void* l) {
    __builtin_amdgcn_global_load_lds((const __attribute__((address_space(1))) void*)g,
                                     (__attribute__((address_space(3))) void*)l,
                                     16, 0, 0);
}

// ---------------------------------------------------------------------------
// 128x256 tile i8 MFMA GEMM. 4 waves 2x2, each wave 64m x 128n as 4x8 tiles
// of mfma_i32_16x16x64_i8 — the champion shape. R8 = minimal clean T4:
// 3-slot LDS ring (72 KB -> still 2 blocks/CU), per 64-B tile:
//   STAGE(t+1) -> s_waitcnt vmcnt(6) -> raw s_barrier -> ds_reads -> 32 MFMA
// ONE barrier per tile; vmcnt NEVER 0 in the main loop (6 = tile t+1 stays
// in flight across the barrier). No sched_barrier (m141/R1/R2: -26..-42%
// poison; not needed — ds_reads are C++ loads so the compiler tracks the
// MFMA dependency itself). No __syncthreads in-loop (R6: its vmcnt(0)
// drains the JUST-issued stage = full latency exposure; 160 us).
//
// Safety (derived, relies on in-order lgkm retirement):
//  - visibility: barrier(t) follows every wave's vmcnt(6) at iter t, which
//    (FIFO) proves that wave's tile-t loads landed -> after barrier(t) the
//    whole tile t is in LDS.
//  - overwrite: STAGE(t+1) writes slot (t+1)%3, last read at tile t-2.
//    Any wave V consumed its t-2 ds_reads before issuing its t-2 MFMAs
//    (compiler lgkm waits), which precede V's barrier(t-1); W issues
//    STAGE(t+1) after passing barrier(t-1). No overlap.
//
// LDS swizzle (R6-verified on this exact read pattern: absmax=0, conflicts
// =0): 64-B rows; row pairs form 128-B super-rows of 8 16B chunks; chunk p
// of super-row s lives at slot p ^ (s&7). global_load_lds writes LDS
// linearly with the INVERSE permutation on the global source address.
__launch_bounds__(256, 2)
__global__ void gemm_i8(const signed char* __restrict__ xp,
                        const signed char* __restrict__ wp,
                        const float* __restrict__ sx,
                        const float* __restrict__ sw,
                        const float* __restrict__ sy,
                        float* __restrict__ out) {
    __shared__ __align__(16) signed char As[RD][BM * BKB];   // 24 KB
    __shared__ __align__(16) signed char Bs[RD][BN * BKB];   // 48 KB

    const int tid  = threadIdx.x;
    const int lane = tid & 63;
    const int quad = lane >> 4;    // 16B k-chunk within the 64B k-step
    const int l16  = lane & 15;    // row (A) / col (B) within 16
    const int wave = tid >> 6;     // 0..3
    const int wm = wave >> 1;      // 64-row slab
    const int wn = wave & 1;       // 128-col slab
    const int bn = blockIdx.x;     // fast axis (R7 XCD swizzle reverted:
    const int bm = blockIdx.y;     //  it doubled FETCH for ~0 time change)

    const signed char* aG = xp + (size_t)(bm * BM) * K_DIM;
    const signed char* bG = wp + (size_t)(bn * BN) * K_DIM;

    // Staging source offsets. Per tile: A = 512 chunks (2/thread),
    // B = 1024 chunks (4/thread). LDS chunk L: super-row s=L>>3, slot=L&7,
    // global chunk p = slot^(s&7) -> row = 2s+(p>>2), kchunk = p&3.
    int aOff[2], bOff[4];
#pragma unroll
    for (int i = 0; i < 2; i++) {
        int L = i * 256 + tid;
        int s = L >> 3, p = (L & 7) ^ (s & 7);
        aOff[i] = (2 * s + (p >> 2)) * K_DIM + ((p & 3) << 4);
    }
#pragma unroll
    for (int i = 0; i < 4; i++) {
        int L = i * 256 + tid;
        int s = L >> 3, p = (L & 7) ^ (s & 7);
        bOff[i] = (2 * s + (p >> 2)) * K_DIM + ((p & 3) << 4);
    }

    // Fragment read offset for (row = base16 + l16, chunk = quad):
    // byte = base16*64 + (l16>>1)*128 + ((((l16&1)<<2)|quad)^(l16>>1))*16.
    const int rdo = ((l16 >> 1) * 128)
                  + (((((l16 & 1) << 2) | quad) ^ (l16 >> 1)) << 4);

#define STAGE(T, SL) do { const int kk_ = (T) * BKB;                        \
        signed char* da_ = &As[SL][0];                                      \
        signed char* db_ = &Bs[SL][0];                                      \
        g2lds16(aG + aOff[0] + kk_, da_ + tid * 16);                        \
        g2lds16(aG + aOff[1] + kk_, da_ + 4096 + tid * 16);                 \
        g2lds16(bG + bOff[0] + kk_, db_ + tid * 16);                        \
        g2lds16(bG + bOff[1] + kk_, db_ + 4096 + tid * 16);                 \
        g2lds16(bG + bOff[2] + kk_, db_ + 8192 + tid * 16);                 \
        g2lds16(bG + bOff[3] + kk_, db_ + 12288 + tid * 16);                \
    } while (0)

    v4i acc[4][8];
#pragma unroll
    for (int i = 0; i < 4; i++)
#pragma unroll
        for (int j = 0; j < 8; j++) acc[i][j] = 0;

    STAGE(0, 0);

    int cs = 0, ns = 1;   // slot of tile t / tile t+1
    for (int t = 0; t < NT; ++t) {
        if (t + 1 < NT) {
            STAGE(t + 1, ns);
            // 12 outstanding max (t + t+1); leave t+1's 6 in flight,
            // prove tile t landed (FIFO vmcnt).
            asm volatile("s_waitcnt vmcnt(6)" ::: "memory");
        } else {
            asm volatile("s_waitcnt vmcnt(0)" ::: "memory");
        }
        __builtin_amdgcn_s_barrier();   // raw: no vmcnt(0) drain

        const signed char* a_lds = &As[cs][0] + wm * 4096 + rdo;
        const signed char* b_lds = &Bs[cs][0] + wn * 8192 + rdo;
        v4i af[4], bf[8];
#pragma unroll
        for (int mt = 0; mt < 4; mt++)
            af[mt] = *(const v4i*)(a_lds + mt * 1024);
#pragma unroll
        for (int nt = 0; nt < 8; nt++)
            bf[nt] = *(const v4i*)(b_lds + nt * 1024);
#pragma unroll
        for (int mt = 0; mt < 4; mt++)
#pragma unroll
            for (int nt = 0; nt < 8; nt++)
                acc[mt][nt] = __builtin_amdgcn_mfma_i32_16x16x64_i8(
                    af[mt], bf[nt], acc[mt][nt], 0, 0, 0);

        cs = ns; ns = ns + 1; if (ns == RD) ns = 0;
    }
#undef STAGE

    // Epilogue: C/D layout: col = lane&15, row = quad*4 + reg.
    const int s_base = bm * BM + wm * 64;
    const int n_base = bn * BN + wn * 128;
#pragma unroll
    for (int mt = 0; mt < 4; mt++) {
#pragma unroll
        for (int r = 0; r < 4; r++) {
            int s = s_base + mt * 16 + quad * 4 + r;
            float rs = sx[s] / sy[s];
            float* orow = out + (size_t)s * N_DIM;
#pragma unroll
            for (int nt = 0; nt < 8; nt++) {
                int n = n_base + nt * 16 + l16;
                float v = rintf((float)acc[mt][nt][r] * (rs * sw[n]));
                v = fminf(fmaxf(v, -128.f), 127.f);
                orow[n] = v;
            }
        }
    }
}

// ---------------------------------------------------------------------------
// Correctness fallback if the workspace is too small for packed operands.
__global__ void gemm_naive(const int* __restrict__ x, const int* __restrict__ w,
                           const float* __restrict__ sx, const float* __restrict__ sw,
                           const float* __restrict__ sy, float* __restrict__ out) {
    int n = blockIdx.x * blockDim.x + threadIdx.x;
    int s = blockIdx.y;
    const int4* xr = (const int4*)(x + (size_t)s * K_DIM);
    const int4* wr = (const int4*)(w + (size_t)n * K_DIM);
    int acc = 0;
    for (int k = 0; k < K_DIM / 4; k++) {
        int4 a = xr[k], b = wr[k];
        acc += a.x * b.x + a.y * b.y + a.z * b.z + a.w * b.w;
    }
    float v = rintf((float)acc * (sx[s] / sy[s] * sw[n]));
    out[(size_t)s * N_DIM + n] = fminf(fmaxf(v, -128.f), 127.f);
}

// ---------------------------------------------------------------------------
extern "C" void kernel_launch(void* const* d_in, const int* in_sizes, int n_in,
                              void* d_out, int out_size, void* d_ws, size_t ws_size,
                              hipStream_t stream) {
    const int*   x  = (const int*)d_in[0];     // [S, K] int8 values widened to int32
    const int*   wq = (const int*)d_in[1];     // [N, K]
    const float* sx = (const float*)d_in[2];   // [S]
    const float* sw = (const float*)d_in[3];   // [N]
    const float* sy = (const float*)d_in[4];   // [S]
    float* out = (float*)d_out;                // [S*N out_q] ++ [S scale_y], float32

    const size_t need = (size_t)S_DIM * K_DIM + (size_t)N_DIM * K_DIM;  // 48 MiB
    if (ws_size >= need) {
        signed char* xp = (signed char*)d_ws;
        signed char* wp = xp + (size_t)S_DIM * K_DIM;
        const int nprep = (S_DIM * K_DIM / 4) + (N_DIM * K_DIM / 4) + S_DIM;
        prep<<<dim3((nprep + 255) / 256), dim3(256), 0, stream>>>(
            x, wq, sy, (int*)xp, out);
        gemm_i8<<<dim3(N_DIM / BN, S_DIM / BM), dim3(256), 0, stream>>>(
            xp, wp, sx, sw, sy, out);
    } else {
        copy_sy<<<dim3((S_DIM + 255) / 256), dim3(256), 0, stream>>>(sy, out);
        gemm_naive<<<dim3(N_DIM / 256, S_DIM), dim3(256), 0, stream>>>(
            x, wq, sx, sw, sy, out);
    }
}